// Round 4
// baseline (119.174 us; speedup 1.0000x reference)
//
#include <hip/hip_runtime.h>
#include <hip/hip_bf16.h>

#define N 8192
#define FIN 512
#define FOUT 64
#define NW 256            // mask words per row = N/32
#define L2E 1.44269504089f
#define SPLIT 16

typedef __attribute__((address_space(1))) const void* gas_cptr;
typedef __attribute__((address_space(3))) void* las_ptr;
typedef float f32x4 __attribute__((ext_vector_type(4)));
typedef short bf16x8 __attribute__((ext_vector_type(8)));

#if __has_builtin(__builtin_amdgcn_exp2f)
#define EXP2(x) __builtin_amdgcn_exp2f(x)
#else
#define EXP2(x) exp2f(x)
#endif

static __device__ __forceinline__ unsigned short f2bf_rne(float f) {
  unsigned u = __float_as_uint(f);
  u += 0x7FFFu + ((u >> 16) & 1u);
  return (unsigned short)(u >> 16);
}
static __device__ __forceinline__ unsigned fkey(float f) {
  unsigned u = __float_as_uint(f);
  return (u & 0x80000000u) ? ~u : (u | 0x80000000u);
}

// ---- K0: pack adj (int32 0/1) -> bitmask, row-sequential streaming --------
// 4096 blocks x 256 thr; block handles 2 rows; each wave streams half a row.
__global__ __launch_bounds__(256) void k_pack(
    const int* __restrict__ adj, unsigned* __restrict__ mask) {
  const int t = threadIdx.x;
  const int w = t >> 6, ll = t & 63;
  const int row = blockIdx.x * 2 + (w >> 1);
  const int jbase = (w & 1) * (N / 2);
  const int* arow = adj + (size_t)row * N + jbase;
  unsigned* mrow = mask + (size_t)row * NW + (jbase >> 5);
#pragma unroll 1
  for (int it = 0; it < 64; it += 4) {
    int x0 = arow[(it + 0) * 64 + ll];
    int x1 = arow[(it + 1) * 64 + ll];
    int x2 = arow[(it + 2) * 64 + ll];
    int x3 = arow[(it + 3) * 64 + ll];
    unsigned long long b0 = __ballot(x0 != 0);
    unsigned long long b1 = __ballot(x1 != 0);
    unsigned long long b2 = __ballot(x2 != 0);
    unsigned long long b3 = __ballot(x3 != 0);
    if (ll == 0) {
      *reinterpret_cast<uint4*>(&mrow[it * 2]) =
          make_uint4((unsigned)b0, (unsigned)(b0 >> 32),
                     (unsigned)b1, (unsigned)(b1 >> 32));
      *reinterpret_cast<uint4*>(&mrow[it * 2 + 4]) =
          make_uint4((unsigned)b2, (unsigned)(b2 >> 32),
                     (unsigned)b3, (unsigned)(b3 >> 32));
    }
  }
}

// ---- K1: WhT(bf16) = (h @ W)^T via bf16 MFMA; src2/dst2 = (Wh@a)*log2e ----
__global__ __launch_bounds__(256) void k_wh(
    const float* __restrict__ h, const float* __restrict__ W,
    const float* __restrict__ a, unsigned short* __restrict__ WhT,
    float* __restrict__ src2, float* __restrict__ dst2,
    unsigned* __restrict__ dmaxk) {
  __shared__ __attribute__((aligned(16))) char wts[64 * 512 * 2];   // [f][k] swz
  __shared__ __attribute__((aligned(16))) char hsb[2][64 * 64 * 2]; // [row][k] swz

  const int t = threadIdx.x;
  const int w = t >> 6;
  const int ll = t & 63;
  const int lc = ll & 15;
  const int row0 = blockIdx.x * 64;

  {
    const int k0 = t * 2;
#pragma unroll
    for (int f4 = 0; f4 < 16; ++f4) {
      float4 x0 = *reinterpret_cast<const float4*>(&W[(size_t)k0 * FOUT + f4 * 4]);
      float4 x1 = *reinterpret_cast<const float4*>(&W[(size_t)(k0 + 1) * FOUT + f4 * 4]);
      const float e0[4] = {x0.x, x0.y, x0.z, x0.w};
      const float e1[4] = {x1.x, x1.y, x1.z, x1.w};
#pragma unroll
      for (int e = 0; e < 4; ++e) {
        int f = f4 * 4 + e;
        int bb = f * 1024 + k0 * 2;
        bb ^= (f & 7) << 4;
        *reinterpret_cast<ushort2*>(wts + bb) =
            make_ushort2(f2bf_rne(e0[e]), f2bf_rne(e1[e]));
      }
    }
  }
  __syncthreads();

  f32x4 acc[4];
#pragma unroll
  for (int c = 0; c < 4; ++c) acc[c] = (f32x4){0.f, 0.f, 0.f, 0.f};

  const int hrow = 16 * w + (ll >> 2);
  const float* hbase = &h[(size_t)(row0 + hrow) * FIN + (ll & 3) * 16];

#define LOADH(dst, kc)                                                        \
  do {                                                                        \
    dst[0] = *reinterpret_cast<const float4*>(hbase + (kc));                  \
    dst[1] = *reinterpret_cast<const float4*>(hbase + (kc) + 4);              \
    dst[2] = *reinterpret_cast<const float4*>(hbase + (kc) + 8);              \
    dst[3] = *reinterpret_cast<const float4*>(hbase + (kc) + 12);             \
  } while (0)

#define WRITEH(buf, src)                                                      \
  do {                                                                        \
    int bb0 = hrow * 128 + (ll & 3) * 32;                                     \
    bb0 ^= (hrow & 7) << 4;                                                   \
    _Pragma("unroll") for (int q = 0; q < 4; ++q) {                           \
      ushort4 u = make_ushort4(f2bf_rne(src[q].x), f2bf_rne(src[q].y),        \
                               f2bf_rne(src[q].z), f2bf_rne(src[q].w));       \
      *reinterpret_cast<ushort4*>(hsb[buf] + (bb0 ^ (q * 8))) = u;            \
    }                                                                         \
  } while (0)

#define MFMA_CHUNK(buf, kcb)                                                  \
  do {                                                                        \
    _Pragma("unroll") for (int k0 = 0; k0 < 2; ++k0) {                        \
      int arow = 16 * w + lc;                                                 \
      int ab = arow * 128 + k0 * 64 + ((ll >> 4) << 4);                       \
      ab ^= (arow & 7) << 4;                                                  \
      bf16x8 af = *reinterpret_cast<const bf16x8*>(hsb[buf] + ab);            \
      _Pragma("unroll") for (int c = 0; c < 4; ++c) {                         \
        int f = c * 16 + lc;                                                  \
        int bb = f * 1024 + (kcb) + k0 * 64 + ((ll >> 4) << 4);               \
        bb ^= (f & 7) << 4;                                                   \
        bf16x8 bfr = *reinterpret_cast<const bf16x8*>(wts + bb);              \
        acc[c] = __builtin_amdgcn_mfma_f32_16x16x32_bf16(af, bfr, acc[c], 0, 0, 0); \
      }                                                                       \
    }                                                                         \
  } while (0)

  float4 ha[4], hb[4];
  LOADH(ha, 0);
#pragma unroll
  for (int c2 = 0; c2 < 4; ++c2) {
    WRITEH(0, ha);
    LOADH(hb, (2 * c2 + 1) * 64);
    MFMA_CHUNK(0, (2 * c2) * 128);
    WRITEH(1, hb);
    if (c2 < 3) LOADH(ha, (2 * c2 + 2) * 64);
    MFMA_CHUNK(1, (2 * c2 + 1) * 128);
  }

  float a1v[4], a2v[4];
#pragma unroll
  for (int c = 0; c < 4; ++c) {
    a1v[c] = a[c * 16 + lc];
    a2v[c] = a[FOUT + c * 16 + lc];
  }
  float p1[4], p2[4];
#pragma unroll
  for (int q = 0; q < 4; ++q) {
    p1[q] = acc[0][q] * a1v[0] + acc[1][q] * a1v[1] + acc[2][q] * a1v[2] + acc[3][q] * a1v[3];
    p2[q] = acc[0][q] * a2v[0] + acc[1][q] * a2v[1] + acc[2][q] * a2v[2] + acc[3][q] * a2v[3];
  }
#pragma unroll
  for (int msk = 8; msk >= 1; msk >>= 1)
#pragma unroll
    for (int q = 0; q < 4; ++q) {
      p1[q] += __shfl_xor(p1[q], msk);
      p2[q] += __shfl_xor(p2[q], msk);
    }
#pragma unroll
  for (int q = 0; q < 4; ++q) { p1[q] *= L2E; p2[q] *= L2E; }

  const int r0 = row0 + 16 * w + ((ll >> 4) << 2);
  if (lc == 0) {
#pragma unroll
    for (int q = 0; q < 4; ++q) { src2[r0 + q] = p1[q]; dst2[r0 + q] = p2[q]; }
  }
#pragma unroll
  for (int c = 0; c < 4; ++c) {
    ushort4 u = make_ushort4(f2bf_rne(acc[c][0]), f2bf_rne(acc[c][1]),
                             f2bf_rne(acc[c][2]), f2bf_rne(acc[c][3]));
    *reinterpret_cast<ushort4*>(&WhT[(size_t)(c * 16 + lc) * N + r0]) = u;
  }
  float wm = fmaxf(fmaxf(p2[0], p2[1]), fmaxf(p2[2], p2[3]));
  wm = fmaxf(wm, __shfl_xor(wm, 16));
  wm = fmaxf(wm, __shfl_xor(wm, 32));
  if (ll == 0) atomicMax(dmaxk, fkey(wm));
#undef LOADH
#undef WRITEH
#undef MFMA_CHUNK
}

// ---- K2: fused masked softmax (fixed bound) + bf16 MFMA PV ----------------
// adj replaced by L2-resident bitmask: 4 word loads per thread-tile.
__global__ __launch_bounds__(256) void k_attn(
    const unsigned* __restrict__ mask, const unsigned short* __restrict__ WhT,
    const float* __restrict__ src2, const float* __restrict__ dst2,
    const unsigned* __restrict__ dmaxk, float* __restrict__ out,
    float* __restrict__ Opart, float* __restrict__ lpart, const int split) {
  __shared__ __attribute__((aligned(16))) char whs[2 * 8192];  // [f][j] bf16 swz
  __shared__ __attribute__((aligned(16))) char pbs[8192];      // [i][j] bf16 swz

  const int t = threadIdx.x;
  const int w = t >> 6;
  const int ll = t & 63;
  const int rg = t >> 4;
  const int cg = t & 15;
  const int i0 = rg * 4;
  const int row0 = blockIdx.x * 64;
  const int jlen = N / split;
  const int jbase = blockIdx.y * jlen;
  const int ntiles = jlen / 64;

  unsigned kk = dmaxk[0];
  const float dmax2 = (kk & 0x80000000u) ? __uint_as_float(kk & 0x7FFFFFFFu)
                                         : __uint_as_float(~kk);

  float s2v[4], m2[4], l[4];
#pragma unroll
  for (int r = 0; r < 4; ++r) {
    s2v[r] = src2[row0 + i0 + r];
    float x = s2v[r] + dmax2;
    m2[r] = fmaxf(x, 0.2f * x);
    l[r] = 0.f;
  }

  f32x4 acc[4];
#pragma unroll
  for (int c = 0; c < 4; ++c) acc[c] = (f32x4){0.f, 0.f, 0.f, 0.f};

#define STAGE_WHS(buf, j0)                                                    \
  do {                                                                        \
    _Pragma("unroll") for (int i_ = 0; i_ < 2; ++i_) {                        \
      int slot = t + i_ * 256;                                                \
      int b = slot * 16;                                                      \
      int u = b ^ (((b >> 7) & 7) << 4);                                      \
      int f_ = u >> 7;                                                        \
      int jl = (u & 127) >> 1;                                                \
      __builtin_amdgcn_global_load_lds(                                       \
          (gas_cptr)(WhT + (size_t)f_ * N + (j0) + jl),                       \
          (las_ptr)(whs + (buf)*8192 + b), 16, 0, 0);                         \
    }                                                                         \
  } while (0)

#define LOAD_MSK(MW, DV, j0)                                                  \
  do {                                                                        \
    int wi_ = ((j0) >> 5) + (cg >> 3);                                        \
    _Pragma("unroll") for (int r_ = 0; r_ < 4; ++r_)                          \
      MW[r_] = mask[(size_t)(row0 + i0 + r_) * NW + wi_];                     \
    float4 d_ = *reinterpret_cast<const float4*>(&dst2[(j0) + cg * 4]);       \
    DV[0] = d_.x; DV[1] = d_.y; DV[2] = d_.z; DV[3] = d_.w;                   \
  } while (0)

  unsigned mw[4], nmw[4];
  float dv[4], ndv[4];
  STAGE_WHS(0, jbase);
  LOAD_MSK(mw, dv, jbase);

  const int bsh = (cg & 7) * 4;  // this thread's 4 bits start here

  for (int jt = 0; jt < ntiles; ++jt) {
    const int cur = jt & 1;
    __syncthreads();  // whs[cur] DMA (issued a full tile ago) drained

    if (jt + 1 < ntiles) {
      STAGE_WHS(cur ^ 1, jbase + (jt + 1) * 64);
      LOAD_MSK(nmw, ndv, jbase + (jt + 1) * 64);
    }

    // softmax phase (log2 domain, fixed bound m2)
    float p[4][4];
#pragma unroll
    for (int r = 0; r < 4; ++r) {
      unsigned b = mw[r] >> bsh;
#pragma unroll
      for (int jj = 0; jj < 4; ++jj) {
        float x = s2v[r] + dv[jj];
        float e2 = fmaxf(x, 0.2f * x);
        float pe = EXP2(e2 - m2[r]);
        pe = (b & (1u << jj)) ? pe : 0.f;
        p[r][jj] = pe;
        l[r] += pe;
      }
    }
    // pack P rows (wave-private) into pbs, swizzled
#pragma unroll
    for (int r = 0; r < 4; ++r) {
      unsigned u0 = __float_as_uint(p[r][0]);
      unsigned u1 = __float_as_uint(p[r][1]);
      unsigned u2 = __float_as_uint(p[r][2]);
      unsigned u3 = __float_as_uint(p[r][3]);
      uint2 pk = make_uint2((u0 >> 16) | (u1 & 0xFFFF0000u),
                            (u2 >> 16) | (u3 & 0xFFFF0000u));
      int row = i0 + r;
      int ba = (row << 7) + (cg << 3);
      ba ^= (row & 7) << 4;
      *reinterpret_cast<uint2*>(pbs + ba) = pk;
    }

    // MFMA PV (A rows = this wave's pbs rows; B = whs[cur])
    {
      const int lc = ll & 15;
      const int g16 = (ll >> 4) << 4;
#pragma unroll
      for (int k0 = 0; k0 < 2; ++k0) {
        int arow = 16 * w + lc;
        int ab = (arow << 7) + k0 * 64 + g16;
        ab ^= (arow & 7) << 4;
        bf16x8 af = *reinterpret_cast<const bf16x8*>(pbs + ab);
#pragma unroll
        for (int c = 0; c < 4; ++c) {
          int brow = c * 16 + lc;
          int bb = (brow << 7) + k0 * 64 + g16;
          bb ^= (brow & 7) << 4;
          bf16x8 bfr = *reinterpret_cast<const bf16x8*>(whs + cur * 8192 + bb);
          acc[c] = __builtin_amdgcn_mfma_f32_16x16x32_bf16(af, bfr, acc[c], 0, 0, 0);
        }
      }
    }

    if (jt + 1 < ntiles) {
#pragma unroll
      for (int r = 0; r < 4; ++r) { mw[r] = nmw[r]; dv[r] = ndv[r]; }
    }
  }

  // reduce l over the 16 cg lanes
#pragma unroll
  for (int msk = 8; msk >= 1; msk >>= 1)
#pragma unroll
    for (int r = 0; r < 4; ++r) l[r] += __shfl_xor(l[r], msk);

  const int orow = row0 + 16 * w + ((ll >> 4) << 2);
  const int ocol = ll & 15;
  if (split == 1) {
#pragma unroll
    for (int c = 0; c < 4; ++c)
#pragma unroll
      for (int q = 0; q < 4; ++q)
        out[(size_t)(orow + q) * FOUT + c * 16 + ocol] = acc[c][q] / l[q];
  } else {
    const int pb = blockIdx.y;
#pragma unroll
    for (int c = 0; c < 4; ++c)
#pragma unroll
      for (int q = 0; q < 4; ++q)
        Opart[((size_t)pb * N + orow + q) * FOUT + c * 16 + ocol] = acc[c][q];
    if (cg == 0) {
#pragma unroll
      for (int r = 0; r < 4; ++r)
        lpart[(size_t)pb * N + row0 + i0 + r] = l[r];
    }
  }
#undef STAGE_WHS
#undef LOAD_MSK
}

// ---- K3: combine split partials (shared m => plain sums) ------------------
__global__ __launch_bounds__(256) void k_combine(
    const float* __restrict__ Opart, const float* __restrict__ lpart,
    float* __restrict__ out, const int split) {
  int idx = blockIdx.x * 256 + threadIdx.x;
  int row = idx >> 6;
  float num = 0.f, den = 0.f;
  for (int k = 0; k < split; ++k) {
    num += Opart[(size_t)k * N * FOUT + idx];
    den += lpart[(size_t)k * N + row];
  }
  out[idx] = num / den;
}

// ---- launcher --------------------------------------------------------------
extern "C" void kernel_launch(void* const* d_in, const int* in_sizes, int n_in,
                              void* d_out, int out_size, void* d_ws, size_t ws_size,
                              hipStream_t stream) {
  const float* h = (const float*)d_in[0];
  const int* adj = (const int*)d_in[1];
  const float* W = (const float*)d_in[2];
  const float* a = (const float*)d_in[3];
  float* out = (float*)d_out;

  unsigned short* WhT = (unsigned short*)d_ws;  // 64*N bf16 = 1MB
  float* src2 = (float*)(WhT + (size_t)FOUT * N);
  float* dst2 = src2 + N;
  unsigned* dmaxk = (unsigned*)(dst2 + N);
  unsigned* mask = dmaxk + 64;                  // N*NW uints = 8MB
  float* Opart = (float*)(mask + (size_t)N * NW);

  const size_t base_bytes = (size_t)FOUT * N * 2 + 2 * N * 4 + 256 +
                            (size_t)N * NW * 4;
  int split = SPLIT;
  while (split > 1 &&
         base_bytes + (size_t)split * ((size_t)N * FOUT + N) * 4 > ws_size)
    split >>= 1;
  float* lpart = Opart + (size_t)split * N * FOUT;

  hipMemsetAsync(dmaxk, 0, 4, stream);
  k_pack<<<dim3(N / 2), 256, 0, stream>>>(adj, mask);
  k_wh<<<dim3(N / 64), 256, 0, stream>>>(h, W, a, WhT, src2, dst2, dmaxk);
  k_attn<<<dim3(N / 64, split), 256, 0, stream>>>(mask, WhT, src2, dst2, dmaxk,
                                                  out, Opart, lpart, split);
  if (split > 1)
    k_combine<<<dim3((N * FOUT) / 256), 256, 0, stream>>>(Opart, lpart, out, split);
}